// Round 1
// baseline (71.391 us; speedup 1.0000x reference)
//
#include <hip/hip_runtime.h>
#include <cfloat>

// Problem constants (from reference): N=2048, D=1024, K=256 centroids, NG=512 groups.
#define NROWS 2048
#define DDIM  1024
#define KCEN  256
#define NBINS 2048   // uniform bins over [mid[0], mid[254]]; u16 table = 4 KB LDS

// One block per row, 256 threads; each thread handles 4 scalars = 2 rotation pairs.
__global__ __launch_bounds__(256)
void planar_quant_kernel(const float* __restrict__ x,
                         const float* __restrict__ cen,   // [256] sorted
                         const float* __restrict__ rot,   // [512*2] = (cos,sin) per group
                         float* __restrict__ out_xhat,    // [N*D]
                         float* __restrict__ out_idx)     // [N*D] as float values
{
    __shared__ float s_cen[KCEN];
    __shared__ float s_mid[KCEN];            // s_mid[255] = FLT_MAX sentinel
    __shared__ unsigned short s_base[NBINS]; // lower-bound index at each bin start
    __shared__ float s_red[4];
    __shared__ float s_norm;

    const int row = blockIdx.x;
    const int t   = threadIdx.x;

    // Global loads up front (independent, coalesced).
    const float4 xv = *(const float4*)(x + (size_t)row * DDIM + 4 * t);
    const float4 rv = *(const float4*)(rot + 4 * t);   // (c0,s0,c1,s1)
    const float  cv = cen[t];

    s_cen[t] = cv;

    // Row norm: per-thread sum of squares -> wave shuffle reduce -> cross-wave LDS.
    float ss = xv.x * xv.x + xv.y * xv.y + xv.z * xv.z + xv.w * xv.w;
    #pragma unroll
    for (int off = 32; off >= 1; off >>= 1)
        ss += __shfl_xor(ss, off, 64);
    if ((t & 63) == 0) s_red[t >> 6] = ss;

    __syncthreads();   // s_cen + s_red visible

    if (t == 0) {
        const float tot = s_red[0] + s_red[1] + s_red[2] + s_red[3];
        s_norm = fmaxf(sqrtf(tot), 1e-8f);
    }

    // Uniform bin-map constants; computed redundantly per thread (deterministic, so
    // identical across build and query — required for the exactness argument).
    const float lo    = 0.5f * (s_cen[0] + s_cen[1]);                 // = mid[0]
    const float hi    = 0.5f * (s_cen[KCEN - 2] + s_cen[KCEN - 1]);   // = mid[254]
    const float invw  = (float)NBINS / fmaxf(hi - lo, 1e-30f);
    const float nbm1f = (float)(NBINS - 1);

    // Monotone nondecreasing in m (fp sub/mul-by-positive/clamp/trunc all monotone).
    // binOf(a) < binOf(b)  =>  a < b, which makes the table walk exact.
#define BIN_OF(m) ((int)fminf(fmaxf(((m) - (lo)) * invw, 0.0f), nbm1f))

    // Thread t derives mid[t-1] and mid[t] locally from s_cen (no extra barrier),
    // publishes s_mid[t], and fills s_base over the bin span (bin(mid[t-1]), bin(mid[t])].
    // fp adds are commutative, so thread t's jc == thread t+1's jp exactly: the spans
    // tile [0, NBINS) with no gaps and no races.
    {
        const float cm    = s_cen[(t > 0) ? (t - 1) : 0];
        const float cp    = s_cen[(t < KCEN - 1) ? (t + 1) : (KCEN - 1)];
        const float mid_c = (t < KCEN - 1) ? 0.5f * (cv + cp) : FLT_MAX;
        s_mid[t] = mid_c;

        const int jc = BIN_OF(mid_c);                       // t=255: BIN_OF(FLT_MAX) = NBINS-1
        const int jp = (t > 0) ? BIN_OF(0.5f * (cm + cv)) : -1;
        for (int b = jp + 1; b <= jc; ++b)
            s_base[b] = (unsigned short)t;                  // = count(mids with binOf < b)
    }

    __syncthreads();   // s_mid, s_base, s_norm visible

    const float nrm = s_norm;
    const float inv = 1.0f / nrm;

    // Rotate each pair.
    const float v0 = xv.x * inv, v1 = xv.y * inv, v2 = xv.z * inv, v3 = xv.w * inv;

    const float r0 = rv.x * v0 - rv.y * v1;   // c0*v0 - s0*v1
    const float r1 = rv.y * v0 + rv.x * v1;   // s0*v0 + c0*v1
    const float r2 = rv.z * v2 - rv.w * v3;
    const float r3 = rv.w * v2 + rv.z * v3;

    // Table seed: start <= true lower bound, all skipped mids provably < v.
    int i0 = s_base[BIN_OF(r0)];
    int i1 = s_base[BIN_OF(r1)];
    int i2 = s_base[BIN_OF(r2)];
    int i3 = s_base[BIN_OF(r3)];

    // Fused 4-element forward walk to the exact lower bound (count of mids < v).
    // Sentinel s_mid[255]=FLT_MAX bounds idx at 255. Values concentrate around
    // idx~128 (sigma ~3 indices), so reads are near-broadcast; wave-max iters ~2-3.
    while (true) {
        const float m0 = s_mid[i0], m1 = s_mid[i1], m2 = s_mid[i2], m3 = s_mid[i3];
        const int c0 = m0 < r0, c1 = m1 < r1, c2 = m2 < r2, c3 = m3 < r3;
        if (!__any(c0 | c1 | c2 | c3)) break;
        i0 += c0; i1 += c1; i2 += c2; i3 += c3;
    }

    // Neighbor fix-up with exact distances (argmin picks lowest index on ties) —
    // identical semantics to the previous kernel.
    const int   ii[4] = {i0, i1, i2, i3};
    const float rr[4] = {r0, r1, r2, r3};
    int   qi[4];
    float qv[4];
    #pragma unroll
    for (int e = 0; e < 4; ++e) {
        const int   idx = ii[e];
        const float v   = rr[e];
        const int   im  = (idx > 0) ? idx - 1 : 0;
        const int   ip  = (idx < KCEN - 1) ? idx + 1 : KCEN - 1;
        const float cc  = s_cen[idx];
        const float cl  = s_cen[im];
        const float cr  = s_cen[ip];
        const float best = fabsf(v - cc);
        if (idx > 0 && fabsf(v - cl) <= best)            { qi[e] = im;  qv[e] = cl; }
        else if (idx < KCEN - 1 && fabsf(v - cr) < best) { qi[e] = ip;  qv[e] = cr; }
        else                                             { qi[e] = idx; qv[e] = cc; }
    }

    // Inverse rotation + rescale.
    float4 xh;
    xh.x = ( rv.x * qv[0] + rv.y * qv[1]) * nrm;   //  c*q0 + s*q1
    xh.y = (-rv.y * qv[0] + rv.x * qv[1]) * nrm;   // -s*q0 + c*q1
    xh.z = ( rv.z * qv[2] + rv.w * qv[3]) * nrm;
    xh.w = (-rv.w * qv[2] + rv.z * qv[3]) * nrm;

    float4 fi;
    fi.x = (float)qi[0]; fi.y = (float)qi[1]; fi.z = (float)qi[2]; fi.w = (float)qi[3];

    const size_t off = (size_t)row * DDIM + 4 * t;
    *(float4*)(out_xhat + off) = xh;
    *(float4*)(out_idx  + off) = fi;
#undef BIN_OF
}

extern "C" void kernel_launch(void* const* d_in, const int* in_sizes, int n_in,
                              void* d_out, int out_size, void* d_ws, size_t ws_size,
                              hipStream_t stream) {
    const float* x   = (const float*)d_in[0];   // [2048*1024]
    const float* cen = (const float*)d_in[1];   // [256]
    const float* rot = (const float*)d_in[2];   // [1024]
    float* out       = (float*)d_out;           // [2 * 2048*1024]

    planar_quant_kernel<<<NROWS, 256, 0, stream>>>(
        x, cen, rot, out, out + (size_t)NROWS * DDIM);
}

// Round 2
// 71.194 us; speedup vs baseline: 1.0028x; 1.0028x over previous
//
#include <hip/hip_runtime.h>
#include <cfloat>

// Problem constants: N=2048, D=1024, K=256 centroids, NG=512 groups.
#define NROWS 2048
#define DDIM  1024
#define KCEN  256
#define NBINS 2048   // uniform bins over [mid[0], mid[254]]; u16 table = 4 KB LDS
#define RPB   4      // rows per block = waves per block

// 4 waves/block, one ROW PER WAVE: norm reduce is pure in-wave shuffle (no barrier,
// no LDS round-trip, no thread-0 serialization). One __syncthreads per block total
// (centroid/mid/bin-table staging), amortized over 4 rows. 16 elems/lane => 4x ILP.
__global__ __launch_bounds__(256)
void planar_quant_kernel(const float* __restrict__ x,
                         const float* __restrict__ cen,   // [256] sorted
                         const float* __restrict__ rot,   // [512*2] = (cos,sin)
                         float* __restrict__ out_xhat,    // [N*D]
                         float* __restrict__ out_idx)     // [N*D] as float values
{
    __shared__ float s_cen[KCEN];
    __shared__ float s_mid[KCEN];            // s_mid[255] = FLT_MAX sentinel
    __shared__ unsigned short s_base[NBINS]; // lower-bound index at each bin start

    const int t    = threadIdx.x;
    const int lane = t & 63;
    const int wave = t >> 6;
    const int row  = blockIdx.x * RPB + wave;
    const size_t rbase = (size_t)row * DDIM;

    // ---- global loads up front: 4 coalesced float4 chunks (stride 256 floats) ----
    // Chunk c covers elements [256c + 4*lane .. +3] = 2 complete rotation pairs.
    float4 xv[4], rv[4];
    #pragma unroll
    for (int c = 0; c < 4; ++c) {
        const int off = 256 * c + 4 * lane;
        xv[c] = *(const float4*)(x   + rbase + off);
        rv[c] = *(const float4*)(rot + off);
    }

    // ---- stage centroids + mids + bin table (256 threads, once per block) ----
    // Neighbors read from GLOBAL (L2-hot, uniform-ish) so no pre-barrier is needed.
    const float cv = cen[t];
    const float cm = (t > 0)        ? cen[t - 1] : cv;
    const float cp = (t < KCEN - 1) ? cen[t + 1] : cv;
    s_cen[t] = cv;

    const float lo    = 0.5f * (cen[0] + cen[1]);                 // = mid[0]
    const float hi    = 0.5f * (cen[KCEN - 2] + cen[KCEN - 1]);   // = mid[254]
    const float invw  = (float)NBINS / fmaxf(hi - lo, 1e-30f);
    const float nbm1f = (float)(NBINS - 1);
    // Monotone nondecreasing in m => table walk below is an exact lower bound.
#define BIN_OF(m) ((int)fminf(fmaxf(((m) - lo) * invw, 0.0f), nbm1f))

    const float mid_c = (t < KCEN - 1) ? 0.5f * (cv + cp) : FLT_MAX;
    s_mid[t] = mid_c;
    {
        // Thread t fills bins (BIN_OF(mid[t-1]), BIN_OF(mid[t])]; spans tile [0,NBINS)
        // exactly (thread t's jp == thread t-1's jc bit-for-bit).
        const int jc = BIN_OF(mid_c);                       // t=255: BIN_OF(FLT_MAX)=NBINS-1
        const int jp = (t > 0) ? BIN_OF(0.5f * (cm + cv)) : -1;
        for (int b = jp + 1; b <= jc; ++b)
            s_base[b] = (unsigned short)t;
    }

    // ---- row norm: in-wave butterfly only (overlaps with staging; no barrier) ----
    float ss = 0.f;
    #pragma unroll
    for (int c = 0; c < 4; ++c)
        ss += xv[c].x * xv[c].x + xv[c].y * xv[c].y
            + xv[c].z * xv[c].z + xv[c].w * xv[c].w;
    #pragma unroll
    for (int off = 32; off >= 1; off >>= 1)
        ss += __shfl_xor(ss, off, 64);
    const float nrm = fmaxf(sqrtf(ss), 1e-8f);
    const float inv = 1.0f / nrm;

    __syncthreads();   // the ONLY block barrier: s_cen/s_mid/s_base visible

    // ---- rotate all 16 elements ----
    float r[16];
    #pragma unroll
    for (int c = 0; c < 4; ++c) {
        const float v0 = xv[c].x * inv, v1 = xv[c].y * inv;
        const float v2 = xv[c].z * inv, v3 = xv[c].w * inv;
        r[4*c + 0] = rv[c].x * v0 - rv[c].y * v1;   // c*v0 - s*v1
        r[4*c + 1] = rv[c].y * v0 + rv[c].x * v1;   // s*v0 + c*v1
        r[4*c + 2] = rv[c].z * v2 - rv[c].w * v3;
        r[4*c + 3] = rv[c].w * v2 + rv[c].z * v3;
    }

    // ---- seed from bin table (16 independent u16 reads) ----
    int idx[16];
    #pragma unroll
    for (int e = 0; e < 16; ++e)
        idx[e] = s_base[BIN_OF(r[e])];

    // ---- fused 16-element forward walk to the exact lower bound ----
    // All skipped mids provably < v; sentinel bounds idx at 255. Values concentrate
    // near idx~128 => near-broadcast reads, wave-max ~2-4 iterations.
    while (true) {
        int any = 0;
        #pragma unroll
        for (int e = 0; e < 16; ++e) {
            const int c = s_mid[idx[e]] < r[e];
            any |= c;
            idx[e] += c;
        }
        if (!__any(any)) break;
    }

    // ---- exact-distance neighbor fix-up (argmin lowest-index tie semantics) ----
    float qv[16];
    #pragma unroll
    for (int e = 0; e < 16; ++e) {
        const int   i  = idx[e];
        const float v  = r[e];
        const int   im = (i > 0) ? i - 1 : 0;
        const int   ip = (i < KCEN - 1) ? i + 1 : KCEN - 1;
        const float cc = s_cen[i];
        const float cl = s_cen[im];
        const float cr = s_cen[ip];
        const float best = fabsf(v - cc);
        if (i > 0 && fabsf(v - cl) <= best)            { idx[e] = im; qv[e] = cl; }
        else if (i < KCEN - 1 && fabsf(v - cr) < best) { idx[e] = ip; qv[e] = cr; }
        else                                           { qv[e] = cc; }
    }

    // ---- inverse rotate, rescale, coalesced float4 stores ----
    #pragma unroll
    for (int c = 0; c < 4; ++c) {
        float4 xh, fi;
        xh.x = ( rv[c].x * qv[4*c + 0] + rv[c].y * qv[4*c + 1]) * nrm;  //  c*q0 + s*q1
        xh.y = (-rv[c].y * qv[4*c + 0] + rv[c].x * qv[4*c + 1]) * nrm;  // -s*q0 + c*q1
        xh.z = ( rv[c].z * qv[4*c + 2] + rv[c].w * qv[4*c + 3]) * nrm;
        xh.w = (-rv[c].w * qv[4*c + 2] + rv[c].z * qv[4*c + 3]) * nrm;
        fi.x = (float)idx[4*c + 0]; fi.y = (float)idx[4*c + 1];
        fi.z = (float)idx[4*c + 2]; fi.w = (float)idx[4*c + 3];
        const size_t off = rbase + 256 * c + 4 * lane;
        *(float4*)(out_xhat + off) = xh;
        *(float4*)(out_idx  + off) = fi;
    }
#undef BIN_OF
}

extern "C" void kernel_launch(void* const* d_in, const int* in_sizes, int n_in,
                              void* d_out, int out_size, void* d_ws, size_t ws_size,
                              hipStream_t stream) {
    const float* x   = (const float*)d_in[0];   // [2048*1024]
    const float* cen = (const float*)d_in[1];   // [256]
    const float* rot = (const float*)d_in[2];   // [1024]
    float* out       = (float*)d_out;           // [2 * 2048*1024]

    planar_quant_kernel<<<NROWS / RPB, 256, 0, stream>>>(
        x, cen, rot, out, out + (size_t)NROWS * DDIM);
}